// Round 4
// baseline (1883.876 us; speedup 1.0000x reference)
//
#include <hip/hip_runtime.h>
#include <hip/hip_bf16.h>
#include <initializer_list>

// CSNet on MI355X — round 4.
// r3 -> r4: k_conv drops weight-LDS (B-frags direct from L2-resident Wp),
// LDS 62.8 -> 25.9 KB => 4 wg/CU; epilogue staged through ibuf in halves.
// k_last rewritten with LDS halo tiling (kills 2.6x over-fetch).
// Activations NHWC bf16: act[n][y][x][c=64].
// d_out: out[16*65536] | outcsy[16*16384] | initrec[16*65536]  (fp32)
// d_ws:  A[16 img] bf16 | Bt[nc img] bf16 | Wp[36864] bf16

#define HW 65536
#define IMG 4194304        // 64*HW elems per image

typedef __attribute__((ext_vector_type(8))) short short8;
typedef __attribute__((ext_vector_type(4))) float f32x4;

__device__ __forceinline__ float bf2f(unsigned short u) {
    union { unsigned u; float f; } v; v.u = ((unsigned)u) << 16; return v.f;
}
__device__ __forceinline__ unsigned short f2bf(float f) {
    union { float f; unsigned u; } v; v.f = f;
    unsigned r = v.u + 0x7FFF + ((v.u >> 16) & 1);   // RNE
    return (unsigned short)(r >> 16);
}

// ---------------- K1: CS sampling conv (stride 32, 32x32 kernel) ----------------
__global__ void k_cs(const float* __restrict__ x, const float* __restrict__ Wcs,
                     float* __restrict__ outcsy)
{
    __shared__ float xs[1024];
    const int bid = blockIdx.x;            // n*64 + hb*8 + wb
    const int wb = bid & 7, hb = (bid >> 3) & 7, n = bid >> 6;
    const int tid = threadIdx.x;
    for (int idx = tid; idx < 1024; idx += 256) {
        int i = idx >> 5, j = idx & 31;
        xs[idx] = x[(long)n * HW + (hb * 32 + i) * 256 + wb * 32 + j];
    }
    __syncthreads();
    const int c = tid;
    const float4* W4 = (const float4*)(Wcs + (long)c * 1024);
    float acc = 0.f;
#pragma unroll 4
    for (int k4 = 0; k4 < 256; ++k4) {
        float4 wv = W4[k4];
        acc += wv.x * xs[4 * k4] + wv.y * xs[4 * k4 + 1] +
               wv.z * xs[4 * k4 + 2] + wv.w * xs[4 * k4 + 3];
    }
    outcsy[(long)n * 16384 + c * 64 + hb * 8 + wb] = acc;
}

// ---------------- K2: 1x1 init conv + depth-to-space ----------------
__global__ void k_init(const float* __restrict__ outcsy, const float* __restrict__ Winit,
                       float* __restrict__ initrec)
{
    __shared__ float ys[256];
    const int bid = blockIdx.x;
    const int wb = bid & 7, hb = (bid >> 3) & 7, n = bid >> 6;
    const int tid = threadIdx.x;
    ys[tid] = outcsy[(long)n * 16384 + tid * 64 + hb * 8 + wb];
    __syncthreads();
    for (int t = 0; t < 4; ++t) {
        int p = t * 256 + tid;          // p = i*32 + j
        int i = p >> 5, j = p & 31;
        int cc = j * 32 + i;
        const float4* W4 = (const float4*)(Winit + (long)cc * 256);
        float acc = 0.f;
#pragma unroll 4
        for (int c4 = 0; c4 < 64; ++c4) {
            float4 wv = W4[c4];
            acc += wv.x * ys[4 * c4] + wv.y * ys[4 * c4 + 1] +
                   wv.z * ys[4 * c4 + 2] + wv.w * ys[4 * c4 + 3];
        }
        initrec[(long)n * HW + (hb * 32 + i) * 256 + wb * 32 + j] = acc;
    }
}

// ---------------- K3: first conv 1->64 + PReLU, NHWC bf16 out ----------------
__global__ __launch_bounds__(256) void k_first(const float* __restrict__ initrec,
        const float* __restrict__ Wf, unsigned short* __restrict__ A,
        const float* __restrict__ alpha_p)
{
    const int tid = threadIdx.x;
    const int w = tid >> 6, lane = tid & 63;
    const long p0 = (long)blockIdx.x * 64 + w * 16;   // 16 consecutive x, same row
    const int n = (int)(p0 >> 16);
    const int y = (int)((p0 >> 8) & 255);
    const int xb = (int)(p0 & 255);
    float wf[9];
#pragma unroll
    for (int k = 0; k < 9; ++k) wf[k] = Wf[lane * 9 + k];
    const float alpha = alpha_p[0];
    const float* ip = initrec + (long)n * HW;
    for (int i = 0; i < 16; ++i) {
        int x = xb + i;
        float acc = 0.f;
#pragma unroll
        for (int ky = 0; ky < 3; ++ky) {
            int yy = y + ky - 1;
            if ((unsigned)yy >= 256u) continue;
#pragma unroll
            for (int kx = 0; kx < 3; ++kx) {
                int xx = x + kx - 1;
                if ((unsigned)xx >= 256u) continue;
                acc += wf[ky * 3 + kx] * ip[yy * 256 + xx];
            }
        }
        acc = acc >= 0.f ? acc : alpha * acc;
        A[(p0 + i) * 64 + lane] = f2bf(acc);
    }
}

// ---------------- weight prep: fp32 [co][ci][3][3] -> bf16 B-fragment order ----------------
// Wp[cc][tap][nt][lane][j] = W[co=nt*16+(lane&15)][ci=cc*32+(lane>>4)*8+j][tap]
__global__ void k_wprep(const float* __restrict__ Wb, unsigned short* __restrict__ Wp)
{
    int e = blockIdx.x * 256 + threadIdx.x;   // 36864 total
    int cc = e / 18432, r = e % 18432;
    int tap = r / 2048, r2 = r % 2048;
    int nt = (r2 >> 9) & 3, l = (r2 >> 3) & 63, j = r2 & 7;
    int co = nt * 16 + (l & 15);
    int ci = cc * 32 + (l >> 4) * 8 + j;
    Wp[e] = f2bf(Wb[co * 576 + ci * 9 + tap]);
}

// ---------------- K4: 64->64 3x3 conv via MFMA, NHWC bf16 ----------------
// MODE 0: dst = prelu(conv(src));  MODE 1: dst = prelu(res + conv(src))
// wg = 4 waves; tile 16y x 16x x 64co. Wave w: rows 4w..4w+3.
// B-frags read directly from Wp (L2-hot, per-lane coalesced 16 B).
template <int MODE>
__global__ __launch_bounds__(256, 4) void k_conv(const unsigned short* __restrict__ src,
        const unsigned short* __restrict__ res, unsigned short* __restrict__ dst,
        const unsigned short* __restrict__ Wp, const float* __restrict__ alpha_p)
{
    __shared__ short ibuf[12960];  // 25.9 KB: halo 18x18 px x 32 ci, pixel stride 40 shorts

    const int tid = threadIdx.x;
    const int bid = blockIdx.x;
    const int tx = bid & 15, ty = (bid >> 4) & 15, n = bid >> 8;  // n chunk-local
    const int x0 = tx * 16, y0 = ty * 16;
    const int w = tid >> 6, lane = tid & 63;
    const int q = lane >> 4, mm = lane & 15;

    const f32x4 zz = {0.f, 0.f, 0.f, 0.f};
    f32x4 acc[4][4];
#pragma unroll
    for (int mt = 0; mt < 4; ++mt)
#pragma unroll
        for (int nt = 0; nt < 4; ++nt) acc[mt][nt] = zz;

    const unsigned short* sb = src + (long)n * IMG;

    for (int cc = 0; cc < 2; ++cc) {
        // stage input halo (18x18 px, 32 ci of this chunk, zero-pad boundary)
#pragma unroll
        for (int i = 0; i < 6; ++i) {
            int idx = tid + 256 * i;          // 1296 chunks of 16 B
            if (idx < 1296) {
                int pix = idx >> 2, part = idx & 3;
                int row = pix / 18, col = pix - row * 18;
                int gy = y0 + row - 1, gx = x0 + col - 1;
                short8 v = {0, 0, 0, 0, 0, 0, 0, 0};
                if ((unsigned)gy < 256u && (unsigned)gx < 256u)
                    v = *(const short8*)&sb[((long)gy * 256 + gx) * 64 + cc * 32 + part * 8];
                *(short8*)&ibuf[pix * 40 + part * 8] = v;
            }
        }
        __syncthreads();

#pragma unroll
        for (int tap = 0; tap < 9; ++tap) {
            const int ky = tap / 3, kx = tap - ky * 3;
            short8 bf[4];
#pragma unroll
            for (int nt = 0; nt < 4; ++nt)
                bf[nt] = *(const short8*)&Wp[(size_t)cc * 18432 +
                                             (size_t)((tap * 4 + nt) * 64 + lane) * 8];
#pragma unroll
            for (int mt = 0; mt < 4; ++mt) {
                const int ri = 4 * w + mt + ky;      // halo row
                const int cl = mm + kx;              // halo col (per-lane m)
                short8 af = *(const short8*)&ibuf[(ri * 18 + cl) * 40 + q * 8];
#pragma unroll
                for (int nt = 0; nt < 4; ++nt)
                    acc[mt][nt] = __builtin_amdgcn_mfma_f32_16x16x32_bf16(
                        af, bf[nt], acc[mt][nt], 0, 0, 0);
            }
        }
        __syncthreads();
    }

    // epilogue: acc -> LDS in two 8-row halves (reuses ibuf), coalesced stores
    unsigned short* ob = (unsigned short*)ibuf;      // needs 8192 shorts <= 12960
    const float alpha = alpha_p[0];
#pragma unroll
    for (int h = 0; h < 2; ++h) {
        if ((w >> 1) == h) {
#pragma unroll
            for (int mt = 0; mt < 4; ++mt) {
                int row = 4 * w + mt - 8 * h;        // 0..7 within half
#pragma unroll
                for (int nt = 0; nt < 4; ++nt)
#pragma unroll
                    for (int r = 0; r < 4; ++r) {
                        int xx = q * 4 + r;          // D row = (lane>>4)*4 + reg = x pos
                        ob[(row * 16 + xx) * 64 + nt * 16 + mm] = f2bf(acc[mt][nt][r]);
                    }
            }
        }
        __syncthreads();
#pragma unroll
        for (int i = 0; i < 4; ++i) {
            int e = (tid + 256 * i) * 8;             // 1024 chunks of 8 shorts
            int co = e & 63, xx = (e >> 6) & 15, row = 8 * h + (e >> 10);
            long g = (((long)n * 256 + y0 + row) * 256 + (x0 + xx)) * 64 + co;
            short8 cv = *(short8*)&ob[e];
            short8 rv = {0, 0, 0, 0, 0, 0, 0, 0};
            if (MODE == 1) rv = *(const short8*)&res[g];
            short8 ov;
#pragma unroll
            for (int j = 0; j < 8; ++j) {
                float v = bf2f((unsigned short)cv[j]);
                if (MODE == 1) v += bf2f((unsigned short)rv[j]);
                v = (v >= 0.f) ? v : alpha * v;
                ov[j] = (short)f2bf(v);
            }
            *(short8*)&dst[g] = ov;
        }
        __syncthreads();
    }
}

// ---------------- K5: last conv (A + initrec) -> 1 channel, LDS halo tiled ----------------
__global__ __launch_bounds__(256) void k_last(const unsigned short* __restrict__ A,
        const float* __restrict__ initrec, const float* __restrict__ Wl,
        float* __restrict__ out0)
{
    __shared__ short ibuf[23328];        // 18*18 px * 72-short stride = 46.7 KB
    const int bid = blockIdx.x;          // n*256 + ty*16 + tx
    const int tx = bid & 15, ty = (bid >> 4) & 15, n = bid >> 8;
    const int x0 = tx * 16, y0 = ty * 16;
    const int tid = threadIdx.x;
    const unsigned short* Ab = A + (long)n * IMG;

    // stage 18x18 halo (64 ch = 8 x 16B per px), zero-padded
#pragma unroll
    for (int i = 0; i < 11; ++i) {
        int idx = tid + 256 * i;         // 2592 chunks
        if (idx < 2592) {
            int pix = idx >> 3, part = idx & 7;
            int row = pix / 18, col = pix - row * 18;
            int gy = y0 + row - 1, gx = x0 + col - 1;
            short8 v = {0, 0, 0, 0, 0, 0, 0, 0};
            if ((unsigned)gy < 256u && (unsigned)gx < 256u)
                v = *(const short8*)&Ab[((long)gy * 256 + gx) * 64 + part * 8];
            *(short8*)&ibuf[pix * 72 + part * 8] = v;
        }
    }
    __syncthreads();

    // per-tap summed weight for the initrec (broadcast) term — uniform scalar math
    float wsum[9];
#pragma unroll
    for (int k = 0; k < 9; ++k) wsum[k] = 0.f;
    for (int ci = 0; ci < 64; ++ci)
#pragma unroll
        for (int k = 0; k < 9; ++k) wsum[k] += Wl[ci * 9 + k];

    const int x = tid & 15, y = tid >> 4;
    const float* ip = initrec + (long)n * HW;
    float acc = 0.f;
#pragma unroll
    for (int ky = 0; ky < 3; ++ky) {
#pragma unroll
        for (int kx = 0; kx < 3; ++kx) {
            const int tap = ky * 3 + kx;
            const short* p = &ibuf[((y + ky) * 18 + (x + kx)) * 72];
#pragma unroll
            for (int c8 = 0; c8 < 8; ++c8) {
                short8 av = *(const short8*)&p[c8 * 8];
#pragma unroll
                for (int j = 0; j < 8; ++j)
                    acc += Wl[(c8 * 8 + j) * 9 + tap] * bf2f((unsigned short)av[j]);
            }
            int gy = y0 + y + ky - 1, gx = x0 + x + kx - 1;
            if ((unsigned)gy < 256u && (unsigned)gx < 256u)
                acc += wsum[tap] * ip[gy * 256 + gx];
        }
    }
    out0[((long)n * 256 + y0 + y) * 256 + (x0 + x)] = acc;
}

extern "C" void kernel_launch(void* const* d_in, const int* in_sizes, int n_in,
                              void* d_out, int out_size, void* d_ws, size_t ws_size,
                              hipStream_t stream)
{
    const float* x     = (const float*)d_in[0];
    const float* Wcs   = (const float*)d_in[1];
    const float* Winit = (const float*)d_in[2];
    const float* Wf    = (const float*)d_in[3];
    const float* Wb    = (const float*)d_in[4];
    const float* Wl    = (const float*)d_in[5];
    const float* amain = (const float*)d_in[6];
    const float* ablk  = (const float*)d_in[7];

    float* out0    = (float*)d_out;
    float* outcsy  = out0 + 1048576;
    float* initrec = outcsy + 262144;

    unsigned short* A = (unsigned short*)d_ws;        // [16] img bf16 NHWC
    int nc = 1;
    for (int c : {16, 8, 4, 2, 1})
        if ((size_t)(16 + c) * IMG * 2 + 73728 <= ws_size) { nc = c; break; }
    unsigned short* Bt = A + (size_t)16 * IMG;        // [nc] img temp
    unsigned short* Wp = Bt + (size_t)nc * IMG;       // 36864 bf16

    k_cs<<<1024, 256, 0, stream>>>(x, Wcs, outcsy);
    k_init<<<1024, 256, 0, stream>>>(outcsy, Winit, initrec);
    k_wprep<<<144, 256, 0, stream>>>(Wb, Wp);
    k_first<<<16384, 256, 0, stream>>>(initrec, Wf, A, amain);

    for (int i = 0; i < 4; ++i) {
        for (int n0 = 0; n0 < 16; n0 += nc) {
            unsigned short* Ac = A + (size_t)n0 * IMG;
            k_conv<0><<<nc * 256, 256, 0, stream>>>(Ac, (const unsigned short*)nullptr,
                                                    Bt, Wp, ablk);
            k_conv<1><<<nc * 256, 256, 0, stream>>>(Bt, Ac, Ac, Wp, ablk);
        }
    }
    k_last<<<4096, 256, 0, stream>>>(A, initrec, Wl, out0);
}

// Round 5
// 1235.302 us; speedup vs baseline: 1.5250x; 1.5250x over previous
//
#include <hip/hip_runtime.h>
#include <hip/hip_bf16.h>
#include <initializer_list>

// CSNet on MI355X — round 5.
// k_conv: single full-halo LDS stage (46.7 KB, 3 wg/CU), 18-step K-loop with
// zero internal barriers; B-frags from L2 via +1-step register prefetch.
// k_cs/k_init: transposed-weight coalesced streams + LDS broadcast.
// Activations NHWC bf16: act[n][y][x][c=64].
// d_out: out[16*65536] | outcsy[16*16384] | initrec[16*65536]  (fp32)
// d_ws:  A[16 img] | Bt[nc img] | Wp[36864 bf16] | WcsT[256K f32] | WinitT[256K f32]

#define HW 65536
#define IMG 4194304        // 64*HW elems per image

typedef __attribute__((ext_vector_type(8))) short short8;
typedef __attribute__((ext_vector_type(4))) float f32x4;

__device__ __forceinline__ float bf2f(unsigned short u) {
    union { unsigned u; float f; } v; v.u = ((unsigned)u) << 16; return v.f;
}
__device__ __forceinline__ unsigned short f2bf(float f) {
    union { float f; unsigned u; } v; v.f = f;
    unsigned r = v.u + 0x7FFF + ((v.u >> 16) & 1);   // RNE
    return (unsigned short)(r >> 16);
}

// ---------------- weight transposes (one-time prep) ----------------
__global__ void k_wcsT(const float* __restrict__ Wcs, float* __restrict__ WT)
{
    int e = blockIdx.x * 256 + threadIdx.x;   // 262144
    int k = e >> 8, c = e & 255;
    WT[(long)k * 256 + c] = Wcs[(long)c * 1024 + k];
}

__global__ void k_winitT(const float* __restrict__ Wi, float* __restrict__ WT)
{
    int e = blockIdx.x * 256 + threadIdx.x;   // 262144
    int ci = e >> 10, cc = e & 1023;
    WT[e] = Wi[(long)cc * 256 + ci];
}

// ---------------- K1: CS sampling conv (stride 32, 32x32 kernel) ----------------
// 2 pixels per block; coalesced WT stream + LDS patch broadcast.
__global__ __launch_bounds__(256) void k_cs2(const float* __restrict__ x,
        const float* __restrict__ WT, float* __restrict__ outcsy)
{
    __shared__ float xs[2][1024];
    const int b = blockIdx.x;              // 512 blocks, pixels 2b, 2b+1
    const int tid = threadIdx.x;
#pragma unroll
    for (int t = 0; t < 2; ++t) {
        int p = b * 2 + t;                 // n*64 + hb*8 + wb
        int wb = p & 7, hb = (p >> 3) & 7, n = p >> 6;
#pragma unroll
        for (int i = 0; i < 4; ++i) {
            int k = tid + 256 * i;
            int ii = k >> 5, jj = k & 31;
            xs[t][k] = x[(long)n * HW + (hb * 32 + ii) * 256 + wb * 32 + jj];
        }
    }
    __syncthreads();
    float a0 = 0.f, a1 = 0.f;
    for (int k = 0; k < 1024; k += 8) {
#pragma unroll
        for (int u = 0; u < 8; ++u) {
            float wv = WT[(long)(k + u) * 256 + tid];   // lanes coalesced
            a0 += wv * xs[0][k + u];                    // LDS broadcast
            a1 += wv * xs[1][k + u];
        }
    }
#pragma unroll
    for (int t = 0; t < 2; ++t) {
        int p = b * 2 + t;
        int wb = p & 7, hb = (p >> 3) & 7, n = p >> 6;
        float a = t ? a1 : a0;
        outcsy[(long)n * 16384 + tid * 64 + hb * 8 + wb] = a;
    }
}

// ---------------- K2: 1x1 init conv + depth-to-space ----------------
// block = spatial pos (hb,wb) x 2 images; coalesced WinitT stream.
__global__ __launch_bounds__(256) void k_init2(const float* __restrict__ outcsy,
        const float* __restrict__ WT, float* __restrict__ initrec)
{
    __shared__ float ys[2][256];
    __shared__ float ov[2][1024];
    const int b = blockIdx.x;              // s*8 + np, s = hb*8+wb
    const int np = b & 7, s = b >> 3;
    const int wb = s & 7, hb = s >> 3;
    const int tid = threadIdx.x;
#pragma unroll
    for (int i = 0; i < 2; ++i) {
        int idx = tid + 256 * i;
        int t = idx >> 8, c = idx & 255;
        ys[t][c] = outcsy[(long)(np * 2 + t) * 16384 + c * 64 + s];
    }
    __syncthreads();
#pragma unroll
    for (int q4 = 0; q4 < 4; ++q4) {
        int cc = q4 * 256 + tid;           // cc = j*32+i
        float a0 = 0.f, a1 = 0.f;
        for (int ci = 0; ci < 256; ci += 8) {
#pragma unroll
            for (int u = 0; u < 8; ++u) {
                float wv = WT[(long)(ci + u) * 1024 + cc];  // coalesced
                a0 += wv * ys[0][ci + u];
                a1 += wv * ys[1][ci + u];
            }
        }
        int i = cc & 31, j = cc >> 5;
        ov[0][i * 32 + j] = a0;
        ov[1][i * 32 + j] = a1;
    }
    __syncthreads();
#pragma unroll
    for (int t = 0; t < 2; ++t) {
        int n = np * 2 + t;
#pragma unroll
        for (int i2 = 0; i2 < 4; ++i2) {
            int p = i2 * 256 + tid;        // p = i*32+j
            int i = p >> 5, j = p & 31;
            initrec[(long)n * HW + (hb * 32 + i) * 256 + wb * 32 + j] = ov[t][p];
        }
    }
}

// ---------------- K3: first conv 1->64 + PReLU, NHWC bf16 out ----------------
__global__ __launch_bounds__(256) void k_first(const float* __restrict__ initrec,
        const float* __restrict__ Wf, unsigned short* __restrict__ A,
        const float* __restrict__ alpha_p)
{
    const int tid = threadIdx.x;
    const int w = tid >> 6, lane = tid & 63;
    const long p0 = (long)blockIdx.x * 64 + w * 16;   // 16 consecutive x, same row
    const int n = (int)(p0 >> 16);
    const int y = (int)((p0 >> 8) & 255);
    const int xb = (int)(p0 & 255);
    float wf[9];
#pragma unroll
    for (int k = 0; k < 9; ++k) wf[k] = Wf[lane * 9 + k];
    const float alpha = alpha_p[0];
    const float* ip = initrec + (long)n * HW;
    for (int i = 0; i < 16; ++i) {
        int x = xb + i;
        float acc = 0.f;
#pragma unroll
        for (int ky = 0; ky < 3; ++ky) {
            int yy = y + ky - 1;
            if ((unsigned)yy >= 256u) continue;
#pragma unroll
            for (int kx = 0; kx < 3; ++kx) {
                int xx = x + kx - 1;
                if ((unsigned)xx >= 256u) continue;
                acc += wf[ky * 3 + kx] * ip[yy * 256 + xx];
            }
        }
        acc = acc >= 0.f ? acc : alpha * acc;
        A[(p0 + i) * 64 + lane] = f2bf(acc);
    }
}

// ---------------- weight prep: fp32 [co][ci][3][3] -> bf16 B-fragment order ----------------
// Wp[cc][tap][nt][lane][j] = W[co=nt*16+(lane&15)][ci=cc*32+(lane>>4)*8+j][tap]
__global__ void k_wprep(const float* __restrict__ Wb, unsigned short* __restrict__ Wp)
{
    int e = blockIdx.x * 256 + threadIdx.x;   // 36864 total
    int cc = e / 18432, r = e % 18432;
    int tap = r / 2048, r2 = r % 2048;
    int nt = (r2 >> 9) & 3, l = (r2 >> 3) & 63, j = r2 & 7;
    int co = nt * 16 + (l & 15);
    int ci = cc * 32 + (l >> 4) * 8 + j;
    Wp[e] = f2bf(Wb[co * 576 + ci * 9 + tap]);
}

// ---------------- K4: 64->64 3x3 conv via MFMA, NHWC bf16 ----------------
// MODE 0: dst = prelu(conv(src));  MODE 1: dst = prelu(res + conv(src))
// wg = 4 waves; tile 16y x 16x x 64co; wave w: rows 4w..4w+3.
// Full 64-ci halo staged once (stride 72 shorts); 18 K-steps, no inner barriers;
// B-frags from L2 with +1-step register prefetch.
template <int MODE>
__global__ __launch_bounds__(256, 3) void k_conv(const unsigned short* __restrict__ src,
        const unsigned short* __restrict__ res, unsigned short* __restrict__ dst,
        const unsigned short* __restrict__ Wp, const float* __restrict__ alpha_p)
{
    __shared__ short halo[23328];   // 18*18 px * 72 shorts = 46.7 KB (reused as ob)

    const int tid = threadIdx.x;
    const int bid = blockIdx.x;
    const int tx = bid & 15, ty = (bid >> 4) & 15, n = bid >> 8;  // n chunk-local
    const int x0 = tx * 16, y0 = ty * 16;
    const int w = tid >> 6, lane = tid & 63;
    const int q = lane >> 4, mm = lane & 15;

    // ---- stage full halo: 18x18 px, 64 ci, full-line coalesced ----
    const unsigned short* sb = src + (long)n * IMG;
#pragma unroll
    for (int i = 0; i < 11; ++i) {
        int idx = tid + 256 * i;             // 2592 chunks of 16 B
        if (idx < 2592) {
            int pix = idx >> 3, part = idx & 7;
            int row = pix / 18, col = pix - row * 18;
            int gy = y0 + row - 1, gx = x0 + col - 1;
            short8 v = {0, 0, 0, 0, 0, 0, 0, 0};
            if ((unsigned)gy < 256u && (unsigned)gx < 256u)
                v = *(const short8*)&sb[((long)gy * 256 + gx) * 64 + part * 8];
            *(short8*)&halo[pix * 72 + part * 8] = v;
        }
    }

    // ---- preload B-frags for step 0 (overlaps staging latency) ----
    short8 bcur[4], bnxt[4];
#pragma unroll
    for (int nt = 0; nt < 4; ++nt)
        bcur[nt] = *(const short8*)&Wp[(size_t)(nt * 512 + lane * 8)];

    const f32x4 zz = {0.f, 0.f, 0.f, 0.f};
    f32x4 acc[4][4];
#pragma unroll
    for (int mt = 0; mt < 4; ++mt)
#pragma unroll
        for (int nt = 0; nt < 4; ++nt) acc[mt][nt] = zz;

    __syncthreads();

    const int mmt = mm * 72 + q * 8;
#pragma unroll
    for (int s = 0; s < 18; ++s) {
        const int cc = s / 9, tap = s % 9;
        const int ky = tap / 3, kx = tap % 3;
        const int sn = (s + 1 < 18) ? s + 1 : s;
        const int ccn = sn / 9, tapn = sn % 9;
#pragma unroll
        for (int nt = 0; nt < 4; ++nt)
            bnxt[nt] = *(const short8*)&Wp[(size_t)ccn * 18432 +
                                           (size_t)((tapn * 4 + nt) * 512 + lane * 8)];
        const int soff = ky * 1296 + kx * 72 + cc * 32 + mmt;
#pragma unroll
        for (int mt = 0; mt < 4; ++mt) {
            short8 af = *(const short8*)&halo[(4 * w + mt) * 1296 + soff];
#pragma unroll
            for (int nt = 0; nt < 4; ++nt)
                acc[mt][nt] = __builtin_amdgcn_mfma_f32_16x16x32_bf16(
                    af, bcur[nt], acc[mt][nt], 0, 0, 0);
        }
#pragma unroll
        for (int nt = 0; nt < 4; ++nt) bcur[nt] = bnxt[nt];
    }
    __syncthreads();

    // ---- epilogue: acc -> LDS halves (reuses halo), coalesced stores ----
    unsigned short* ob = (unsigned short*)halo;      // 8192 shorts per half
    const float alpha = alpha_p[0];
#pragma unroll
    for (int h = 0; h < 2; ++h) {
        if ((w >> 1) == h) {
#pragma unroll
            for (int mt = 0; mt < 4; ++mt) {
                int row = 4 * w + mt - 8 * h;        // 0..7 within half
#pragma unroll
                for (int nt = 0; nt < 4; ++nt)
#pragma unroll
                    for (int r = 0; r < 4; ++r) {
                        int xx = q * 4 + r;          // D row = (lane>>4)*4 + reg = x pos
                        ob[(row * 16 + xx) * 64 + nt * 16 + mm] = f2bf(acc[mt][nt][r]);
                    }
            }
        }
        __syncthreads();
#pragma unroll
        for (int i = 0; i < 4; ++i) {
            int e = (tid + 256 * i) * 8;             // 1024 chunks of 8 shorts
            int co = e & 63, xx = (e >> 6) & 15, row = 8 * h + (e >> 10);
            long g = (((long)n * 256 + y0 + row) * 256 + (x0 + xx)) * 64 + co;
            short8 cv = *(short8*)&ob[e];
            short8 rv = {0, 0, 0, 0, 0, 0, 0, 0};
            if (MODE == 1) rv = *(const short8*)&res[g];
            short8 ov;
#pragma unroll
            for (int j = 0; j < 8; ++j) {
                float v = bf2f((unsigned short)cv[j]);
                if (MODE == 1) v += bf2f((unsigned short)rv[j]);
                v = (v >= 0.f) ? v : alpha * v;
                ov[j] = (short)f2bf(v);
            }
            *(short8*)&dst[g] = ov;
        }
        __syncthreads();
    }
}

// ---------------- K5: last conv (A + initrec) -> 1 channel, LDS halo tiled ----------------
__global__ __launch_bounds__(256) void k_last(const unsigned short* __restrict__ A,
        const float* __restrict__ initrec, const float* __restrict__ Wl,
        float* __restrict__ out0)
{
    __shared__ short ibuf[23328];        // 18*18 px * 72-short stride
    const int bid = blockIdx.x;          // n*256 + ty*16 + tx
    const int tx = bid & 15, ty = (bid >> 4) & 15, n = bid >> 8;
    const int x0 = tx * 16, y0 = ty * 16;
    const int tid = threadIdx.x;
    const unsigned short* Ab = A + (long)n * IMG;

#pragma unroll
    for (int i = 0; i < 11; ++i) {
        int idx = tid + 256 * i;         // 2592 chunks
        if (idx < 2592) {
            int pix = idx >> 3, part = idx & 7;
            int row = pix / 18, col = pix - row * 18;
            int gy = y0 + row - 1, gx = x0 + col - 1;
            short8 v = {0, 0, 0, 0, 0, 0, 0, 0};
            if ((unsigned)gy < 256u && (unsigned)gx < 256u)
                v = *(const short8*)&Ab[((long)gy * 256 + gx) * 64 + part * 8];
            *(short8*)&ibuf[pix * 72 + part * 8] = v;
        }
    }
    __syncthreads();

    float wsum[9];
#pragma unroll
    for (int k = 0; k < 9; ++k) wsum[k] = 0.f;
    for (int ci = 0; ci < 64; ++ci)
#pragma unroll
        for (int k = 0; k < 9; ++k) wsum[k] += Wl[ci * 9 + k];

    const int x = tid & 15, y = tid >> 4;
    const float* ip = initrec + (long)n * HW;
    float acc = 0.f;
#pragma unroll
    for (int ky = 0; ky < 3; ++ky) {
#pragma unroll
        for (int kx = 0; kx < 3; ++kx) {
            const int tap = ky * 3 + kx;
            const short* p = &ibuf[((y + ky) * 18 + (x + kx)) * 72];
#pragma unroll
            for (int c8 = 0; c8 < 8; ++c8) {
                short8 av = *(const short8*)&p[c8 * 8];
#pragma unroll
                for (int j = 0; j < 8; ++j)
                    acc += Wl[(c8 * 8 + j) * 9 + tap] * bf2f((unsigned short)av[j]);
            }
            int gy = y0 + y + ky - 1, gx = x0 + x + kx - 1;
            if ((unsigned)gy < 256u && (unsigned)gx < 256u)
                acc += wsum[tap] * ip[gy * 256 + gx];
        }
    }
    out0[((long)n * 256 + y0 + y) * 256 + (x0 + x)] = acc;
}

extern "C" void kernel_launch(void* const* d_in, const int* in_sizes, int n_in,
                              void* d_out, int out_size, void* d_ws, size_t ws_size,
                              hipStream_t stream)
{
    const float* x     = (const float*)d_in[0];
    const float* Wcs   = (const float*)d_in[1];
    const float* Winit = (const float*)d_in[2];
    const float* Wf    = (const float*)d_in[3];
    const float* Wb    = (const float*)d_in[4];
    const float* Wl    = (const float*)d_in[5];
    const float* amain = (const float*)d_in[6];
    const float* ablk  = (const float*)d_in[7];

    float* out0    = (float*)d_out;
    float* outcsy  = out0 + 1048576;
    float* initrec = outcsy + 262144;

    const size_t EXTRA = 73728 + 2 * 1048576;         // Wp + WcsT + WinitT bytes
    unsigned short* A = (unsigned short*)d_ws;        // [16] img bf16 NHWC
    int nc = 1;
    for (int c : {16, 8, 4, 2, 1})
        if ((size_t)(16 + c) * IMG * 2 + EXTRA <= ws_size) { nc = c; break; }
    unsigned short* Bt   = A + (size_t)16 * IMG;      // [nc] img temp
    unsigned short* Wp   = Bt + (size_t)nc * IMG;     // 36864 bf16
    float*          WcsT = (float*)(Wp + 36864);      // 262144 f32
    float*          WinT = WcsT + 262144;             // 262144 f32

    k_wcsT<<<1024, 256, 0, stream>>>(Wcs, WcsT);
    k_winitT<<<1024, 256, 0, stream>>>(Winit, WinT);
    k_wprep<<<144, 256, 0, stream>>>(Wb, Wp);

    k_cs2<<<512, 256, 0, stream>>>(x, WcsT, outcsy);
    k_init2<<<512, 256, 0, stream>>>(outcsy, WinT, initrec);
    k_first<<<16384, 256, 0, stream>>>(initrec, Wf, A, amain);

    for (int i = 0; i < 4; ++i) {
        for (int n0 = 0; n0 < 16; n0 += nc) {
            unsigned short* Ac = A + (size_t)n0 * IMG;
            k_conv<0><<<nc * 256, 256, 0, stream>>>(Ac, (const unsigned short*)nullptr,
                                                    Bt, Wp, ablk);
            k_conv<1><<<nc * 256, 256, 0, stream>>>(Bt, Ac, Ac, Wp, ablk);
        }
    }
    k_last<<<4096, 256, 0, stream>>>(A, initrec, Wl, out0);
}

// Round 6
// 1124.604 us; speedup vs baseline: 1.6751x; 1.0984x over previous
//
#include <hip/hip_runtime.h>
#include <hip/hip_bf16.h>
#include <initializer_list>

// CSNet on MI355X — round 6.
// r5 -> r6: (1) fused residual pair k_res: prelu(src + conv2(prelu(conv1(src))))
// in one kernel — conv1 computed on the 18x18 halo grid into an LDS o2 buffer
// (zeroed outside the image = conv2 zero-padding), conv2 straight from LDS.
// HBM per iteration 742 -> 477 MB. (2) k_first: pixel-per-thread rewrite.
// Activations NHWC bf16: act[n][y][x][c=64].
// d_out: out[16*65536] | outcsy[16*16384] | initrec[16*65536]  (fp32)
// d_ws:  A[16 img] | Bt[nc img] | Wp[36864 bf16] | WcsT[256K f32] | WinitT[256K f32]

#define HW 65536
#define IMG 4194304        // 64*HW elems per image

typedef __attribute__((ext_vector_type(8))) short short8;
typedef __attribute__((ext_vector_type(4))) float f32x4;

__device__ __forceinline__ float bf2f(unsigned short u) {
    union { unsigned u; float f; } v; v.u = ((unsigned)u) << 16; return v.f;
}
__device__ __forceinline__ unsigned short f2bf(float f) {
    union { float f; unsigned u; } v; v.f = f;
    unsigned r = v.u + 0x7FFF + ((v.u >> 16) & 1);   // RNE
    return (unsigned short)(r >> 16);
}

// ---------------- weight transposes (one-time prep) ----------------
__global__ void k_wcsT(const float* __restrict__ Wcs, float* __restrict__ WT)
{
    int e = blockIdx.x * 256 + threadIdx.x;   // 262144
    int k = e >> 8, c = e & 255;
    WT[(long)k * 256 + c] = Wcs[(long)c * 1024 + k];
}

__global__ void k_winitT(const float* __restrict__ Wi, float* __restrict__ WT)
{
    int e = blockIdx.x * 256 + threadIdx.x;   // 262144
    int ci = e >> 10, cc = e & 1023;
    WT[e] = Wi[(long)cc * 256 + ci];
}

// ---------------- K1: CS sampling conv (stride 32, 32x32 kernel) ----------------
__global__ __launch_bounds__(256) void k_cs2(const float* __restrict__ x,
        const float* __restrict__ WT, float* __restrict__ outcsy)
{
    __shared__ float xs[2][1024];
    const int b = blockIdx.x;              // 512 blocks, pixels 2b, 2b+1
    const int tid = threadIdx.x;
#pragma unroll
    for (int t = 0; t < 2; ++t) {
        int p = b * 2 + t;                 // n*64 + hb*8 + wb
        int wb = p & 7, hb = (p >> 3) & 7, n = p >> 6;
#pragma unroll
        for (int i = 0; i < 4; ++i) {
            int k = tid + 256 * i;
            int ii = k >> 5, jj = k & 31;
            xs[t][k] = x[(long)n * HW + (hb * 32 + ii) * 256 + wb * 32 + jj];
        }
    }
    __syncthreads();
    float a0 = 0.f, a1 = 0.f;
    for (int k = 0; k < 1024; k += 8) {
#pragma unroll
        for (int u = 0; u < 8; ++u) {
            float wv = WT[(long)(k + u) * 256 + tid];   // lanes coalesced
            a0 += wv * xs[0][k + u];                    // LDS broadcast
            a1 += wv * xs[1][k + u];
        }
    }
#pragma unroll
    for (int t = 0; t < 2; ++t) {
        int p = b * 2 + t;
        int wb = p & 7, hb = (p >> 3) & 7, n = p >> 6;
        float a = t ? a1 : a0;
        outcsy[(long)n * 16384 + tid * 64 + hb * 8 + wb] = a;
    }
}

// ---------------- K2: 1x1 init conv + depth-to-space ----------------
__global__ __launch_bounds__(256) void k_init2(const float* __restrict__ outcsy,
        const float* __restrict__ WT, float* __restrict__ initrec)
{
    __shared__ float ys[2][256];
    __shared__ float ov[2][1024];
    const int b = blockIdx.x;              // s*8 + np
    const int np = b & 7, s = b >> 3;
    const int wb = s & 7, hb = s >> 3;
    const int tid = threadIdx.x;
#pragma unroll
    for (int i = 0; i < 2; ++i) {
        int idx = tid + 256 * i;
        int t = idx >> 8, c = idx & 255;
        ys[t][c] = outcsy[(long)(np * 2 + t) * 16384 + c * 64 + s];
    }
    __syncthreads();
#pragma unroll
    for (int q4 = 0; q4 < 4; ++q4) {
        int cc = q4 * 256 + tid;           // cc = j*32+i
        float a0 = 0.f, a1 = 0.f;
        for (int ci = 0; ci < 256; ci += 8) {
#pragma unroll
            for (int u = 0; u < 8; ++u) {
                float wv = WT[(long)(ci + u) * 1024 + cc];  // coalesced
                a0 += wv * ys[0][ci + u];
                a1 += wv * ys[1][ci + u];
            }
        }
        int i = cc & 31, j = cc >> 5;
        ov[0][i * 32 + j] = a0;
        ov[1][i * 32 + j] = a1;
    }
    __syncthreads();
#pragma unroll
    for (int t = 0; t < 2; ++t) {
        int n = np * 2 + t;
#pragma unroll
        for (int i2 = 0; i2 < 4; ++i2) {
            int p = i2 * 256 + tid;        // p = i*32+j
            int i = p >> 5, j = p & 31;
            initrec[(long)n * HW + (hb * 32 + i) * 256 + wb * 32 + j] = ov[t][p];
        }
    }
}

// ---------------- K3: first conv 1->64 + PReLU, pixel-per-thread ----------------
__global__ __launch_bounds__(256) void k_first(const float* __restrict__ initrec,
        const float* __restrict__ Wf, unsigned short* __restrict__ A,
        const float* __restrict__ alpha_p)
{
    const int bid = blockIdx.x;            // n*256 + ty*16 + tx
    const int tx = bid & 15, ty = (bid >> 4) & 15, n = bid >> 8;
    const int tid = threadIdx.x;
    const int x = (tx << 4) + (tid & 15), y = (ty << 4) + (tid >> 4);
    const float* ip = initrec + (long)n * HW;

    float in[9];
#pragma unroll
    for (int ky = 0; ky < 3; ++ky)
#pragma unroll
        for (int kx = 0; kx < 3; ++kx) {
            int iy = y + ky - 1, ix = x + kx - 1;
            in[ky * 3 + kx] = ((unsigned)iy < 256u && (unsigned)ix < 256u)
                                  ? ip[iy * 256 + ix] : 0.f;
        }

    const float alpha = alpha_p[0];
    unsigned short* op = &A[(((long)n * 256 + y) * 256 + x) * 64];
#pragma unroll
    for (int c8 = 0; c8 < 8; ++c8) {
        short8 ov;
#pragma unroll
        for (int j = 0; j < 8; ++j) {
            const float* wp = &Wf[(c8 * 8 + j) * 9];   // uniform -> scalar loads
            float a = 0.f;
#pragma unroll
            for (int t = 0; t < 9; ++t) a += wp[t] * in[t];
            a = a >= 0.f ? a : alpha * a;
            ov[j] = (short)f2bf(a);
        }
        *(short8*)&op[c8 * 8] = ov;
    }
}

// ---------------- weight prep: fp32 [co][ci][3][3] -> bf16 B-fragment order ----------------
// Wp[cc][tap][nt][lane][j] = W[co=nt*16+(lane&15)][ci=cc*32+(lane>>4)*8+j][tap]
__global__ void k_wprep(const float* __restrict__ Wb, unsigned short* __restrict__ Wp)
{
    int e = blockIdx.x * 256 + threadIdx.x;   // 36864 total
    int cc = e / 18432, r = e % 18432;
    int tap = r / 2048, r2 = r % 2048;
    int nt = (r2 >> 9) & 3, l = (r2 >> 3) & 63, j = r2 & 7;
    int co = nt * 16 + (l & 15);
    int ci = cc * 32 + (l >> 4) * 8 + j;
    Wp[e] = f2bf(Wb[co * 576 + ci * 9 + tap]);
}

// ---------------- K4: fused residual pair ----------------
// dst = prelu(src + conv2(prelu(conv1(src)))), both convs share Wp weights.
// Tile 16x16 out; conv1 computed on the 18x18 o2 grid; o2 zeroed outside image.
__global__ __launch_bounds__(256, 2) void k_res(const unsigned short* __restrict__ src,
        unsigned short* __restrict__ dst, const unsigned short* __restrict__ Wp,
        const float* __restrict__ alpha_p)
{
    __shared__ short halo[16000];   // 20x20 px * 40 shorts (32 ci chunk) = 32 KB
    __shared__ short o2b[23328];    // 18x18 px * 72 shorts (64 ch)     = 46.7 KB

    const int tid = threadIdx.x;
    const int bid = blockIdx.x;
    const int tx = bid & 15, ty = (bid >> 4) & 15, n = bid >> 8;  // n chunk-local
    const int x0 = tx * 16, y0 = ty * 16;
    const int w = tid >> 6, lane = tid & 63;
    const int q = lane >> 4, mm = lane & 15;
    const float alpha = alpha_p[0];
    const unsigned short* sb = src + (long)n * IMG;

    // per-lane conv1 M-tile pixel bases: tiles t = w + 4i (i<6), p = t*16+mm
    int pb1[6];
#pragma unroll
    for (int i = 0; i < 6; ++i) {
        int p = (w + 4 * i) * 16 + mm;
        p = p < 323 ? p : 323;
        pb1[i] = p + 2 * (p / 18);          // rho*20 + gam
    }

    short8 bcur[4], bnxt[4];
#pragma unroll
    for (int nt = 0; nt < 4; ++nt)
        bcur[nt] = *(const short8*)&Wp[(size_t)(nt * 512 + lane * 8)];

    const f32x4 zz = {0.f, 0.f, 0.f, 0.f};
    f32x4 acc1[6][4];
#pragma unroll
    for (int i = 0; i < 6; ++i)
#pragma unroll
        for (int nt = 0; nt < 4; ++nt) acc1[i][nt] = zz;

    // ======== phase 1: conv1 over the 18x18 grid, ci in 2 chunks ========
    for (int cc = 0; cc < 2; ++cc) {
        if (cc) __syncthreads();            // halo reuse guard
        // stage 20x20 px x 32 ci chunk (zero-padded at image boundary)
#pragma unroll
        for (int i = 0; i < 7; ++i) {
            int idx = tid + 256 * i;        // 1600 chunks of 16 B
            if (idx < 1600) {
                int pix = idx >> 2, part = idx & 3;
                int row = pix / 20, col = pix - row * 20;
                int gy = y0 + row - 2, gx = x0 + col - 2;
                short8 v = {0, 0, 0, 0, 0, 0, 0, 0};
                if ((unsigned)gy < 256u && (unsigned)gx < 256u)
                    v = *(const short8*)&sb[((long)gy * 256 + gx) * 64 + cc * 32 + part * 8];
                *(short8*)&halo[pix * 40 + part * 8] = v;
            }
        }
        __syncthreads();

#pragma unroll
        for (int tap = 0; tap < 9; ++tap) {
            const int s = cc * 9 + tap;
            const int sn = (s + 1) % 18;    // wraps into conv2's step 0
            const int ccn = sn / 9, tapn = sn % 9;
#pragma unroll
            for (int nt = 0; nt < 4; ++nt)
                bnxt[nt] = *(const short8*)&Wp[(size_t)ccn * 18432 +
                                               (size_t)((tapn * 4 + nt) * 512 + lane * 8)];
            const int ky = tap / 3, kx = tap % 3;
            const int toff = (ky * 20 + kx) * 40 + q * 8;
#pragma unroll
            for (int i = 0; i < 6; ++i) {
                short8 af = *(const short8*)&halo[pb1[i] * 40 + toff];
#pragma unroll
                for (int nt = 0; nt < 4; ++nt)
                    acc1[i][nt] = __builtin_amdgcn_mfma_f32_16x16x32_bf16(
                        af, bcur[nt], acc1[i][nt], 0, 0, 0);
            }
#pragma unroll
            for (int nt = 0; nt < 4; ++nt) bcur[nt] = bnxt[nt];
        }
    }

    // ======== write o2 = prelu(conv1) to LDS; zero outside image ========
#pragma unroll
    for (int i = 0; i < 6; ++i) {
        int t = w + 4 * i;
        if (t < 21) {
#pragma unroll
            for (int r = 0; r < 4; ++r) {
                int p = t * 16 + q * 4 + r;          // o2 position (D row = q*4+r)
                p = p < 323 ? p : 323;
                int rho = p / 18, gam = p - 18 * rho;
                bool valid = (unsigned)(y0 - 1 + rho) < 256u &&
                             (unsigned)(x0 - 1 + gam) < 256u;
#pragma unroll
                for (int nt = 0; nt < 4; ++nt) {
                    float v = acc1[i][nt][r];
                    v = v >= 0.f ? v : alpha * v;
                    o2b[p * 72 + nt * 16 + mm] = valid ? (short)f2bf(v) : (short)0;
                }
            }
        }
    }
    __syncthreads();

    // ======== phase 2: conv2 from o2 LDS (rows t = 4w+mt) ========
    f32x4 acc2[4][4];
#pragma unroll
    for (int mt = 0; mt < 4; ++mt)
#pragma unroll
        for (int nt = 0; nt < 4; ++nt) acc2[mt][nt] = zz;

    for (int cc = 0; cc < 2; ++cc) {
#pragma unroll
        for (int tap = 0; tap < 9; ++tap) {
            const int s = cc * 9 + tap;
            const int sn = (s + 1) % 18;
#pragma unroll
            for (int nt = 0; nt < 4; ++nt)
                bnxt[nt] = *(const short8*)&Wp[(size_t)(sn / 9) * 18432 +
                                               (size_t)(((sn % 9) * 4 + nt) * 512 + lane * 8)];
            const int ky = tap / 3, kx = tap % 3;
#pragma unroll
            for (int mt = 0; mt < 4; ++mt) {
                short8 af = *(const short8*)&o2b[((4 * w + mt + ky) * 18 + mm + kx) * 72 +
                                                 cc * 32 + q * 8];
#pragma unroll
                for (int nt = 0; nt < 4; ++nt)
                    acc2[mt][nt] = __builtin_amdgcn_mfma_f32_16x16x32_bf16(
                        af, bcur[nt], acc2[mt][nt], 0, 0, 0);
            }
#pragma unroll
            for (int nt = 0; nt < 4; ++nt) bcur[nt] = bnxt[nt];
        }
    }
    __syncthreads();

    // ======== epilogue: acc2 -> LDS halves, res-add + prelu, coalesced stores ====
    unsigned short* ob = (unsigned short*)o2b;       // 8192 shorts per half
#pragma unroll
    for (int h = 0; h < 2; ++h) {
        if ((w >> 1) == h) {
#pragma unroll
            for (int mt = 0; mt < 4; ++mt) {
                int row = 4 * w + mt - 8 * h;        // 0..7 within half
#pragma unroll
                for (int nt = 0; nt < 4; ++nt)
#pragma unroll
                    for (int r = 0; r < 4; ++r) {
                        int xx = q * 4 + r;
                        ob[(row * 16 + xx) * 64 + nt * 16 + mm] = f2bf(acc2[mt][nt][r]);
                    }
            }
        }
        __syncthreads();
#pragma unroll
        for (int i = 0; i < 4; ++i) {
            int e = (tid + 256 * i) * 8;             // 1024 chunks of 8 shorts
            int co = e & 63, xx = (e >> 6) & 15, row = 8 * h + (e >> 10);
            long g = (((long)n * 256 + y0 + row) * 256 + (x0 + xx)) * 64 + co;
            short8 cv = *(short8*)&ob[e];
            short8 rv = *(const short8*)&src[(long)n * IMG +
                                             ((long)(y0 + row) * 256 + x0 + xx) * 64 + co];
            short8 ov;
#pragma unroll
            for (int j = 0; j < 8; ++j) {
                float v = bf2f((unsigned short)cv[j]) + bf2f((unsigned short)rv[j]);
                v = (v >= 0.f) ? v : alpha * v;
                ov[j] = (short)f2bf(v);
            }
            *(short8*)&dst[(long)n * IMG + ((long)(y0 + row) * 256 + x0 + xx) * 64 + co] = ov;
        }
        __syncthreads();
    }
}

// ---------------- K5: last conv (A + initrec) -> 1 channel, LDS halo tiled ----------------
__global__ __launch_bounds__(256) void k_last(const unsigned short* __restrict__ A,
        const float* __restrict__ initrec, const float* __restrict__ Wl,
        float* __restrict__ out0)
{
    __shared__ short ibuf[23328];        // 18*18 px * 72-short stride
    const int bid = blockIdx.x;          // n*256 + ty*16 + tx
    const int tx = bid & 15, ty = (bid >> 4) & 15, n = bid >> 8;
    const int x0 = tx * 16, y0 = ty * 16;
    const int tid = threadIdx.x;
    const unsigned short* Ab = A + (long)n * IMG;

#pragma unroll
    for (int i = 0; i < 11; ++i) {
        int idx = tid + 256 * i;         // 2592 chunks
        if (idx < 2592) {
            int pix = idx >> 3, part = idx & 7;
            int row = pix / 18, col = pix - row * 18;
            int gy = y0 + row - 1, gx = x0 + col - 1;
            short8 v = {0, 0, 0, 0, 0, 0, 0, 0};
            if ((unsigned)gy < 256u && (unsigned)gx < 256u)
                v = *(const short8*)&Ab[((long)gy * 256 + gx) * 64 + part * 8];
            *(short8*)&ibuf[pix * 72 + part * 8] = v;
        }
    }
    __syncthreads();

    float wsum[9];
#pragma unroll
    for (int k = 0; k < 9; ++k) wsum[k] = 0.f;
    for (int ci = 0; ci < 64; ++ci)
#pragma unroll
        for (int k = 0; k < 9; ++k) wsum[k] += Wl[ci * 9 + k];

    const int x = tid & 15, y = tid >> 4;
    const float* ip = initrec + (long)n * HW;
    float acc = 0.f;
#pragma unroll
    for (int ky = 0; ky < 3; ++ky) {
#pragma unroll
        for (int kx = 0; kx < 3; ++kx) {
            const int tap = ky * 3 + kx;
            const short* p = &ibuf[((y + ky) * 18 + (x + kx)) * 72];
#pragma unroll
            for (int c8 = 0; c8 < 8; ++c8) {
                short8 av = *(const short8*)&p[c8 * 8];
#pragma unroll
                for (int j = 0; j < 8; ++j)
                    acc += Wl[(c8 * 8 + j) * 9 + tap] * bf2f((unsigned short)av[j]);
            }
            int gy = y0 + y + ky - 1, gx = x0 + x + kx - 1;
            if ((unsigned)gy < 256u && (unsigned)gx < 256u)
                acc += wsum[tap] * ip[gy * 256 + gx];
        }
    }
    out0[((long)n * 256 + y0 + y) * 256 + (x0 + x)] = acc;
}

extern "C" void kernel_launch(void* const* d_in, const int* in_sizes, int n_in,
                              void* d_out, int out_size, void* d_ws, size_t ws_size,
                              hipStream_t stream)
{
    const float* x     = (const float*)d_in[0];
    const float* Wcs   = (const float*)d_in[1];
    const float* Winit = (const float*)d_in[2];
    const float* Wf    = (const float*)d_in[3];
    const float* Wb    = (const float*)d_in[4];
    const float* Wl    = (const float*)d_in[5];
    const float* amain = (const float*)d_in[6];
    const float* ablk  = (const float*)d_in[7];

    float* out0    = (float*)d_out;
    float* outcsy  = out0 + 1048576;
    float* initrec = outcsy + 262144;

    const size_t EXTRA = 73728 + 2 * 1048576;         // Wp + WcsT + WinitT bytes
    unsigned short* A = (unsigned short*)d_ws;        // [16] img bf16 NHWC
    int nc = 1;
    for (int c : {16, 8, 4, 2, 1})
        if ((size_t)(16 + c) * IMG * 2 + EXTRA <= ws_size) { nc = c; break; }
    unsigned short* Bt   = A + (size_t)16 * IMG;      // [nc] img temp
    unsigned short* Wp   = Bt + (size_t)nc * IMG;     // 36864 bf16
    float*          WcsT = (float*)(Wp + 36864);      // 262144 f32
    float*          WinT = WcsT + 262144;             // 262144 f32

    k_wcsT<<<1024, 256, 0, stream>>>(Wcs, WcsT);
    k_winitT<<<1024, 256, 0, stream>>>(Winit, WinT);
    k_wprep<<<144, 256, 0, stream>>>(Wb, Wp);

    k_cs2<<<512, 256, 0, stream>>>(x, WcsT, outcsy);
    k_init2<<<512, 256, 0, stream>>>(outcsy, WinT, initrec);
    k_first<<<4096, 256, 0, stream>>>(initrec, Wf, A, amain);

    // 4 residual iterations; per image-chunk, ping-pong A <-> Bt (even count
    // of iterations leaves the result back in A).
    for (int n0 = 0; n0 < 16; n0 += nc) {
        unsigned short* Ac = A + (size_t)n0 * IMG;
        for (int i = 0; i < 4; ++i) {
            const unsigned short* s = (i & 1) ? Bt : Ac;
            unsigned short*       d = (i & 1) ? Ac : Bt;
            k_res<<<nc * 256, 256, 0, stream>>>(s, d, Wp, ablk);
        }
    }
    k_last<<<4096, 256, 0, stream>>>(A, initrec, Wl, out0);
}